// Round 8
// baseline (381.353 us; speedup 1.0000x reference)
//
#include <hip/hip_runtime.h>
#include <hip/hip_bf16.h>
#include <stdint.h>
#include <stddef.h>

typedef __bf16 bf16_t;
typedef __bf16 bf16x4 __attribute__((ext_vector_type(4)));
typedef __bf16 bf16x8 __attribute__((ext_vector_type(8)));
typedef float floatx4 __attribute__((ext_vector_type(4)));

#define NN 20000
#define EE 320000
#define DD 512
#define CAP 96
#define BETA1 0.6931471805599453f
#define BETA2 0.40546510810816444f

// async global->LDS, 16B per lane. LDS dest must be wave-uniform base + lane*16.
__device__ __forceinline__ void gload16(const bf16_t* g, bf16_t* l) {
  __builtin_amdgcn_global_load_lds((const __attribute__((address_space(1))) uint32_t*)g,
                                   (__attribute__((address_space(3))) uint32_t*)l, 16, 0, 0);
}

// ------- bucket fill with degree count: esrc[dst*CAP + cnt[dst]++] = src -----
__global__ __launch_bounds__(256) void bucket_kernel(
    const int* __restrict__ src, const int* __restrict__ dst,
    int* __restrict__ cnt, int* __restrict__ esrc, int E) {
  int e = blockIdx.x * 256 + threadIdx.x;
  if (e < E) {
    int d = dst[e];
    int pos = atomicAdd(&cnt[d], 1);
    if (pos < CAP) esrc[d * CAP + pos] = src[e];
  }
}

// ---------------- fused prep: cnt zero + all weight/input reformats ----------
// sections by blockIdx:
//   [0, 5000)        featb: feat f32 row-major -> bf16 row-major (8 elem/thr)
//   [5000, 5128)     BW0:   fc_w f32 [n][k] -> bf16 row-major (= B^T layout)
//   [5128, 5384)     BT1:   [w1_1; w2_1]^T -> bf16 BT[n][k], k<1024
//   [5384, 5640)     BT2:   [w1_2; w2_2]^T -> bf16
//   [5640, 5719)     cnt zero
#define PREP_BLOCKS 5719
__global__ __launch_bounds__(256) void prep_kernel(
    const float* __restrict__ feat, const float* __restrict__ fc_w,
    const float* __restrict__ w1_1, const float* __restrict__ w2_1,
    const float* __restrict__ w1_2, const float* __restrict__ w2_2,
    bf16_t* __restrict__ featb, bf16_t* __restrict__ bw0,
    bf16_t* __restrict__ bt1, bf16_t* __restrict__ bt2,
    int* __restrict__ cnt) {
  int b = blockIdx.x, t = threadIdx.x;
  if (b < 5128) {
    // straight cvt, 8 f32 -> bf16x8 per thread
    const float* in = (b < 5000) ? feat : fc_w;
    bf16_t* out = (b < 5000) ? featb : bw0;
    size_t c = (size_t)(b < 5000 ? b : b - 5000) * 256 + t;
    const float* s = in + c * 8;
    float4 v0 = *(const float4*)s, v1 = *(const float4*)(s + 4);
    bf16x8 o = {(bf16_t)v0.x, (bf16_t)v0.y, (bf16_t)v0.z, (bf16_t)v0.w,
                (bf16_t)v1.x, (bf16_t)v1.y, (bf16_t)v1.z, (bf16_t)v1.w};
    *(bf16x8*)(out + c * 8) = o;
  } else if (b < 5640) {
    // BT[n][k] = W[k][n], W = [W1; W2] stacked in k. 8 k per thread.
    int base = (b < 5384) ? 5128 : 5384;
    const float* Wa = (b < 5384) ? w1_1 : w1_2;
    const float* Wb = (b < 5384) ? w2_1 : w2_2;
    bf16_t* bt = (b < 5384) ? bt1 : bt2;
    int c = (b - base) * 256 + t;        // [0, 65536)
    int n = c >> 7, kc = c & 127;
    const float* W = (kc < 64) ? Wa : Wb;
    int kcw = kc & 63;
    bf16x8 o;
#pragma unroll
    for (int e = 0; e < 8; ++e)
      o[e] = (bf16_t)W[(size_t)(kcw * 8 + e) * 512 + n];   // column-n gather
    *(bf16x8*)(bt + (size_t)n * 1024 + kc * 8) = o;
  } else {
    int i = (b - 5640) * 256 + t;
    if (i < NN) cnt[i] = 0;
  }
}

// ------------- bucket aggregate: one wave per dst node, lane owns 8 dims -----
// f = 0.9 * nrm[node] * sum_e nrm[src_e] * hin[src_e]
// Acat[node][0:512] = bf16(f)      (second half holds 0.1*h, layer-invariant)
// Depth-8 software pipeline with NAMED registers (dynamic-index arrays spill
// to scratch). Round-2 verified body.
__global__ __launch_bounds__(256) void aggregate_kernel(
    const bf16_t* __restrict__ hin, const float* __restrict__ nrm,
    const int* __restrict__ cnt, const int* __restrict__ esrc,
    bf16_t* __restrict__ Acat) {
  int node = blockIdx.x * 4 + (threadIdx.x >> 6);
  if (node >= NN) return;
  int lane = threadIdx.x & 63;
  const int* eb = esrc + (size_t)node * CAP;
  int n_e = cnt[node];
  n_e = n_e < CAP ? n_e : CAP;

  float acc[8] = {};
  bf16x8 v0 = {}, v1 = {}, v2 = {}, v3 = {}, v4 = {}, v5 = {}, v6 = {}, v7 = {};
  float ns0 = 0, ns1 = 0, ns2 = 0, ns3 = 0, ns4 = 0, ns5 = 0, ns6 = 0, ns7 = 0;

#define LOADJ(j, idx)                                                  \
  {                                                                    \
    int s = eb[idx];                                                   \
    ns##j = nrm[s];                                                    \
    v##j = *(const bf16x8*)(hin + (size_t)s * DD + lane * 8);          \
  }
#define SLOT(j, i)                                                     \
  if ((i) + (j) < n_e) {                                               \
    bf16x8 a = v##j; float na = ns##j;                                 \
    if ((i) + (j) + 8 < n_e) LOADJ(j, (i) + (j) + 8)                   \
    _Pragma("unroll")                                                  \
    for (int k = 0; k < 8; ++k) acc[k] += na * (float)a[k];            \
  }

  if (0 < n_e) LOADJ(0, 0)
  if (1 < n_e) LOADJ(1, 1)
  if (2 < n_e) LOADJ(2, 2)
  if (3 < n_e) LOADJ(3, 3)
  if (4 < n_e) LOADJ(4, 4)
  if (5 < n_e) LOADJ(5, 5)
  if (6 < n_e) LOADJ(6, 6)
  if (7 < n_e) LOADJ(7, 7)

  for (int i = 0; i < n_e; i += 8) {
    SLOT(0, i)
    SLOT(1, i)
    SLOT(2, i)
    SLOT(3, i)
    SLOT(4, i)
    SLOT(5, i)
    SLOT(6, i)
    SLOT(7, i)
  }
#undef SLOT
#undef LOADJ

  float nd = 0.9f * nrm[node];
  bf16x8 ob;
#pragma unroll
  for (int k = 0; k < 8; ++k) ob[k] = (bf16_t)(nd * acc[k]);
  *(bf16x8*)(Acat + (size_t)node * 1024 + lane * 8) = ob;
}

// -------- GEMM: C = A(MxK,bf16) @ B(Kx512), B given transposed BT[n][k] ------
// Round 8: BK=32, 3-buffer ring (36 KB LDS -> 4 blocks/CU, MORE residency than
// round-2's 3) + T4 counted vmcnt. Steady state: stages kt,kt+1 in flight (6
// loads/wave); s_waitcnt vmcnt(3) drains ONLY stage kt; raw s_barrier with
// lgkmcnt(0) (ds_read completion = write-after-read safety) + sched_barrier.
// vmcnt(0) only in the peeled final iteration. Each stage gets ~2 iterations
// of latency cover + 16 waves/CU cross-block overlap; the per-iter vmcnt(0)
// drain of rounds 2/7 is gone.
// LDS swizzle over ROW-PAIRS (8 slots per 128B double-row):
//   chunk (r, gc) at slot8 = (((r&1)<<2)|gc) ^ ((r>>1)&7)
// == round-2's measured-zero-conflict scheme on 128B lines.
// XCD swizzle: bIdx = (m%8) + 8*(n + 4*(m/8)).
// MODE 0: h = acc + bias -> outb bf16; acat2[row*1024+512+col] = bf16(0.1*h);
//         blocks >= 1280 compute nrm[] from cnt[] and exit (norm piggyback).
// MODE 1/2: fs = Acat[row][col] + Acat[row][512+col] (bf16 halves);
//           r = relu((1-beta)*fs + beta*acc + bias) -> MODE1 bf16 outb, MODE2 f32 outf
template <int MODE>
__global__ __launch_bounds__(256) void gemm_kernel(
    const bf16_t* __restrict__ A, const bf16_t* __restrict__ BT,
    int lda, int ldb, int K, int M,
    const float* __restrict__ bias,
    const bf16_t* __restrict__ acat_ro, float beta,
    float* __restrict__ outf, bf16_t* __restrict__ outb,
    bf16_t* __restrict__ acat2,
    const int* __restrict__ cnt, float* __restrict__ nrm) {
  __shared__ bf16_t As[3][64 * 32];    // 4 KB per buf
  __shared__ bf16_t Bs[3][128 * 32];   // 8 KB per buf  -> 36 KB total

  const int bid = blockIdx.x;
  if constexpr (MODE == 0) {
    if (bid >= 1280) {   // norm piggyback blocks
      int i = (bid - 1280) * 256 + threadIdx.x;
      if (i < NN) nrm[i] = 1.0f / sqrtf(fmaxf((float)cnt[i], 1.0f));
      return;
    }
  }
  const int mt = (bid >> 5) * 8 + (bid & 7);   // m-tile
  const int nt = (bid >> 3) & 3;               // n-tile
  const int m0 = mt * 64;
  if (m0 >= M) return;
  const int n0 = nt * 128;

  const int t = threadIdx.x;
  const int lane = t & 63;
  const int w = t >> 6;
  const int wm = w & 1, wn = w >> 1;
  const int quad = lane >> 4, m16 = lane & 15;

  // staging: LDS-linear position p=t (A; t and t+256 for B). Invert swizzle:
  //   high = p>>3; z = (p&7) ^ (high&7); row r = high*2 + (z>>2); chunk gc = z&3
  // ((t+256)>>3 = high+32 -> same (high&7), same z -> row r+64, same gc.)
  const int hi = t >> 3;
  const int z = (t & 7) ^ (hi & 7);
  const int ra = hi * 2 + (z >> 2);
  const int gc = z & 3;
  int arow = m0 + ra; arow = arow < M ? arow : M - 1;  // clamp OOB (tail tile)
  const bf16_t* agp  = A + (size_t)arow * lda + gc * 8;
  const bf16_t* bgp0 = BT + (size_t)(n0 + ra) * ldb + gc * 8;
  const bf16_t* bgp1 = BT + (size_t)(n0 + 64 + ra) * ldb + gc * 8;

#define STAGE(buf, ko)                              \
  gload16(agp + (ko),  &As[buf][t * 8]);            \
  gload16(bgp0 + (ko), &Bs[buf][t * 8]);            \
  gload16(bgp1 + (ko), &Bs[buf][(t + 256) * 8]);

#define COMPUTE(b)                                                               \
  {                                                                              \
    bf16x8 af[2], bfr[4];                                                        \
    _Pragma("unroll")                                                            \
    for (int i = 0; i < 2; ++i) {                                                \
      int ar = wm * 32 + i * 16 + m16;                                           \
      int s8 = (((ar & 1) << 2) | quad) ^ ((ar >> 1) & 7);                       \
      af[i] = *(const bf16x8*)(&As[b][((ar >> 1) * 8 + s8) * 8]);                \
    }                                                                            \
    _Pragma("unroll")                                                            \
    for (int j = 0; j < 4; ++j) {                                                \
      int br = wn * 64 + j * 16 + m16;                                           \
      int s8 = (((br & 1) << 2) | quad) ^ ((br >> 1) & 7);                       \
      bfr[j] = *(const bf16x8*)(&Bs[b][((br >> 1) * 8 + s8) * 8]);               \
    }                                                                            \
    _Pragma("unroll")                                                            \
    for (int i = 0; i < 2; ++i)                                                  \
      _Pragma("unroll")                                                          \
      for (int j = 0; j < 4; ++j)                                                \
        acc[i][j] = __builtin_amdgcn_mfma_f32_16x16x32_bf16(af[i], bfr[j],       \
                                                            acc[i][j], 0, 0, 0); \
  }

  floatx4 acc[2][4] = {};
  const int niter = K >> 5;   // BK=32; 16 or 32 iters (>= 3)

  // prologue: stage buffers 0 and 1 (6 loads in flight per wave)
  STAGE(0, 0)
  STAGE(1, 32)

  int cur = 0, nx = 2;   // slot of kt, slot of kt+2
  for (int kt = 0; kt < niter - 1; ++kt) {
    // outstanding = stages kt,kt+1 (6 loads); drain ONLY stage kt
    asm volatile("s_waitcnt vmcnt(3)" ::: "memory");
    asm volatile("s_waitcnt lgkmcnt(0)" ::: "memory");
    __builtin_amdgcn_s_barrier();
    __builtin_amdgcn_sched_barrier(0);
    if (kt + 2 < niter) {
      const int ko = (kt + 2) * 32;
      STAGE(nx, ko)
    }
    COMPUTE(cur)
    cur = (cur == 2) ? 0 : cur + 1;
    nx = (nx == 2) ? 0 : nx + 1;
  }
  // peeled final iteration: only stage niter-1 outstanding -> full drain
  asm volatile("s_waitcnt vmcnt(0)" ::: "memory");
  asm volatile("s_waitcnt lgkmcnt(0)" ::: "memory");
  __builtin_amdgcn_s_barrier();
  __builtin_amdgcn_sched_barrier(0);
  COMPUTE(cur)

#undef STAGE
#undef COMPUTE

  // epilogue: C/D layout col = lane&15, row = quad*4 + reg
#pragma unroll
  for (int i = 0; i < 2; ++i) {
#pragma unroll
    for (int j = 0; j < 4; ++j) {
      int col = n0 + wn * 64 + j * 16 + m16;
      float bv = bias[col];
#pragma unroll
      for (int p = 0; p < 4; ++p) {
        int row = m0 + wm * 32 + i * 16 + quad * 4 + p;
        if (row < M) {
          size_t idx = (size_t)row * DD + col;
          float v = acc[i][j][p];
          if constexpr (MODE == 0) {
            float hv = v + bv;
            outb[idx] = (bf16_t)hv;
            acat2[(size_t)row * 1024 + 512 + col] = (bf16_t)(0.1f * hv);
          } else {
            float fsv = (float)acat_ro[(size_t)row * 1024 + col] +
                        (float)acat_ro[(size_t)row * 1024 + 512 + col];
            float r = (1.0f - beta) * fsv + beta * v + bv;
            r = fmaxf(r, 0.0f);
            if constexpr (MODE == 1) outb[idx] = (bf16_t)r;
            else outf[idx] = r;
          }
        }
      }
    }
  }
}

extern "C" void kernel_launch(void* const* d_in, const int* in_sizes, int n_in,
                              void* d_out, int out_size, void* d_ws, size_t ws_size,
                              hipStream_t stream) {
  const float* feat = (const float*)d_in[0];
  const int* src = (const int*)d_in[1];
  const int* dst = (const int*)d_in[2];
  const float* fc_w = (const float*)d_in[3];
  const float* fc_b = (const float*)d_in[4];
  const float* w1_1 = (const float*)d_in[5];
  const float* w2_1 = (const float*)d_in[6];
  const float* b_1  = (const float*)d_in[7];
  const float* w1_2 = (const float*)d_in[8];
  const float* w2_2 = (const float*)d_in[9];
  const float* b_2  = (const float*)d_in[10];
  float* out = (float*)d_out;

  char* ws = (char*)d_ws;
  size_t off = 0;
  auto alloc = [&](size_t bytes) {
    char* p = ws + off;
    off += (bytes + 255) & ~(size_t)255;
    return p;
  };
  const size_t NDf = (size_t)NN * DD;               // 10.24M elements
  bf16_t* h_bf   = (bf16_t*)alloc(NDf * sizeof(bf16_t));        // 20.48 MB
  bf16_t* res_bf = (bf16_t*)alloc(NDf * sizeof(bf16_t));        // 20.48 MB
  bf16_t* featb  = (bf16_t*)alloc(NDf * sizeof(bf16_t));        // 20.48 MB
  bf16_t* Acat   = (bf16_t*)alloc((size_t)NN * 1024 * sizeof(bf16_t));  // 40.96 MB
  bf16_t* BW0    = (bf16_t*)alloc((size_t)512 * 512 * sizeof(bf16_t));
  bf16_t* BT1    = (bf16_t*)alloc((size_t)512 * 1024 * sizeof(bf16_t));
  bf16_t* BT2    = (bf16_t*)alloc((size_t)512 * 1024 * sizeof(bf16_t));
  int*    cnt    = (int*)alloc((size_t)NN * sizeof(int));
  float*  nrm    = (float*)alloc((size_t)NN * sizeof(float));
  int*    esrc   = (int*)alloc((size_t)NN * CAP * sizeof(int)); // 7.68 MB

  // 1. fused prep: featb/BW0/BT1/BT2 reformats + cnt zero
  prep_kernel<<<PREP_BLOCKS, 256, 0, stream>>>(feat, fc_w, w1_1, w2_1, w1_2, w2_2,
                                               featb, BW0, BT1, BT2, cnt);
  // 2. bucket build (counts + slots in one pass)
  bucket_kernel<<<(EE + 255) / 256, 256, 0, stream>>>(src, dst, cnt, esrc, EE);

  // 313 m-tiles of 64 rows, 4 n-tiles; swizzled grid covers m<320 -> 1280 blocks
  // 3. h = feat @ fc_w^T + fc_b (h_bf + Acat f0-half); +79 norm piggyback blocks
  gemm_kernel<0><<<1280 + 79, 256, 0, stream>>>(featb, BW0, 512, 512, 512, NN, fc_b,
                                                nullptr, 0.0f, nullptr, h_bf, Acat,
                                                cnt, nrm);

  // ---- layer 1 ----
  aggregate_kernel<<<(NN + 3) / 4, 256, 0, stream>>>(h_bf, nrm, cnt, esrc, Acat);
  gemm_kernel<1><<<1280, 256, 0, stream>>>(Acat, BT1, 1024, 1024, 1024, NN, b_1,
                                           Acat, BETA1, nullptr, res_bf, nullptr,
                                           nullptr, nullptr);

  // ---- layer 2 ----
  aggregate_kernel<<<(NN + 3) / 4, 256, 0, stream>>>(res_bf, nrm, cnt, esrc, Acat);
  gemm_kernel<2><<<1280, 256, 0, stream>>>(Acat, BT2, 1024, 1024, 1024, NN, b_2,
                                           Acat, BETA2, out, nullptr, nullptr,
                                           nullptr, nullptr);
}

// Round 9
// 370.502 us; speedup vs baseline: 1.0293x; 1.0293x over previous
//
#include <hip/hip_runtime.h>
#include <hip/hip_bf16.h>
#include <stdint.h>
#include <stddef.h>

typedef __bf16 bf16_t;
typedef __bf16 bf16x4 __attribute__((ext_vector_type(4)));
typedef __bf16 bf16x8 __attribute__((ext_vector_type(8)));
typedef float floatx4 __attribute__((ext_vector_type(4)));

#define NN 20000
#define EE 320000
#define DD 512
#define CAP 96
#define BETA1 0.6931471805599453f
#define BETA2 0.40546510810816444f

// async global->LDS, 16B per lane. LDS dest must be wave-uniform base + lane*16.
__device__ __forceinline__ void gload16(const bf16_t* g, bf16_t* l) {
  __builtin_amdgcn_global_load_lds((const __attribute__((address_space(1))) uint32_t*)g,
                                   (__attribute__((address_space(3))) uint32_t*)l, 16, 0, 0);
}

// ------- bucket fill with degree count: esrc[dst*CAP + cnt[dst]++] = src -----
__global__ __launch_bounds__(256) void bucket_kernel(
    const int* __restrict__ src, const int* __restrict__ dst,
    int* __restrict__ cnt, int* __restrict__ esrc, int E) {
  int e = blockIdx.x * 256 + threadIdx.x;
  if (e < E) {
    int d = dst[e];
    int pos = atomicAdd(&cnt[d], 1);
    if (pos < CAP) esrc[d * CAP + pos] = src[e];
  }
}

// ---------------- fused prep: cnt zero + all weight/input reformats ----------
// sections by blockIdx:
//   [0, 5000)        featb: feat f32 row-major -> bf16 row-major (8 elem/thr)
//   [5000, 5128)     BW0:   fc_w f32 [n][k] -> bf16 row-major (= B^T layout)
//   [5128, 5384)     BT1:   [w1_1; 0.1*w2_1]^T -> bf16 BT[n][k], k<1024
//   [5384, 5640)     BT2:   [w1_2; 0.1*w2_2]^T -> bf16
//   [5640, 5719)     cnt zero
// 0.1 folded into the W2 half so Acat can hold RAW h (h_bf buffer eliminated):
//   [f,h] @ [W1; 0.1W2]^T = f@W1 + 0.1*(h@W2)
#define PREP_BLOCKS 5719
__global__ __launch_bounds__(256) void prep_kernel(
    const float* __restrict__ feat, const float* __restrict__ fc_w,
    const float* __restrict__ w1_1, const float* __restrict__ w2_1,
    const float* __restrict__ w1_2, const float* __restrict__ w2_2,
    bf16_t* __restrict__ featb, bf16_t* __restrict__ bw0,
    bf16_t* __restrict__ bt1, bf16_t* __restrict__ bt2,
    int* __restrict__ cnt) {
  int b = blockIdx.x, t = threadIdx.x;
  if (b < 5128) {
    // straight cvt, 8 f32 -> bf16x8 per thread
    const float* in = (b < 5000) ? feat : fc_w;
    bf16_t* out = (b < 5000) ? featb : bw0;
    size_t c = (size_t)(b < 5000 ? b : b - 5000) * 256 + t;
    const float* s = in + c * 8;
    float4 v0 = *(const float4*)s, v1 = *(const float4*)(s + 4);
    bf16x8 o = {(bf16_t)v0.x, (bf16_t)v0.y, (bf16_t)v0.z, (bf16_t)v0.w,
                (bf16_t)v1.x, (bf16_t)v1.y, (bf16_t)v1.z, (bf16_t)v1.w};
    *(bf16x8*)(out + c * 8) = o;
  } else if (b < 5640) {
    // BT[n][k] = scale * W[k][n], W = [W1; W2] stacked in k. 8 k per thread.
    int base = (b < 5384) ? 5128 : 5384;
    const float* Wa = (b < 5384) ? w1_1 : w1_2;
    const float* Wb = (b < 5384) ? w2_1 : w2_2;
    bf16_t* bt = (b < 5384) ? bt1 : bt2;
    int c = (b - base) * 256 + t;        // [0, 65536)
    int n = c >> 7, kc = c & 127;
    const float* W = (kc < 64) ? Wa : Wb;
    const float sc = (kc < 64) ? 1.0f : 0.1f;   // fold ALPHA into W2 half
    int kcw = kc & 63;
    bf16x8 o;
#pragma unroll
    for (int e = 0; e < 8; ++e)
      o[e] = (bf16_t)(sc * W[(size_t)(kcw * 8 + e) * 512 + n]);   // column-n gather
    *(bf16x8*)(bt + (size_t)n * 1024 + kc * 8) = o;
  } else {
    int i = (b - 5640) * 256 + t;
    if (i < NN) cnt[i] = 0;
  }
}

// ---------- bucket aggregate: one wave per TWO dst nodes, lane owns 8 dims ---
// f = 0.9 * nrm[node] * sum_e nrm[src_e] * hin[src_e]   (hin row stride param)
// Acat[node][0:512] = bf16(f)    (h-half of Acat untouched, layer-invariant)
// Round 9: DUAL-node per wave, two depth-4 named-register pipelines
// interleaved. Avg degree 16 gives a single 8-deep pipeline only ~2 outer
// iterations; the per-node serial chain (cnt -> eb -> first gathers -> store)
// dominates. Two independent nodes overlap the chains and double issue slots.
// (Dynamic-index arrays spill to scratch -> named regs only.)
__global__ __launch_bounds__(256) void aggregate_kernel(
    const bf16_t* __restrict__ hin, int hstride, const float* __restrict__ nrm,
    const int* __restrict__ cnt, const int* __restrict__ esrc,
    bf16_t* __restrict__ Acat) {
  int nodeA = blockIdx.x * 8 + (threadIdx.x >> 6) * 2;   // 2500*8 = 20000 exact
  int nodeB = nodeA + 1;
  if (nodeA >= NN) return;
  int lane = threadIdx.x & 63;
  const int* ebA = esrc + (size_t)nodeA * CAP;
  const int* ebB = esrc + (size_t)nodeB * CAP;
  int nA = cnt[nodeA]; nA = nA < CAP ? nA : CAP;
  int nB = cnt[nodeB]; nB = nB < CAP ? nB : CAP;
  int nmax = nA > nB ? nA : nB;

  float accA[8] = {}, accB[8] = {};
  bf16x8 va0 = {}, va1 = {}, va2 = {}, va3 = {};
  bf16x8 vb0 = {}, vb1 = {}, vb2 = {}, vb3 = {};
  float sa0 = 0, sa1 = 0, sa2 = 0, sa3 = 0;
  float sb0 = 0, sb1 = 0, sb2 = 0, sb3 = 0;

#define LDA(j, idx)                                                      \
  {                                                                      \
    int s = ebA[idx];                                                    \
    sa##j = nrm[s];                                                      \
    va##j = *(const bf16x8*)(hin + (size_t)s * hstride + lane * 8);      \
  }
#define LDB(j, idx)                                                      \
  {                                                                      \
    int s = ebB[idx];                                                    \
    sb##j = nrm[s];                                                      \
    vb##j = *(const bf16x8*)(hin + (size_t)s * hstride + lane * 8);      \
  }
#define SLA(j, i)                                                        \
  if ((i) + (j) < nA) {                                                  \
    bf16x8 a = va##j; float na = sa##j;                                  \
    if ((i) + (j) + 4 < nA) LDA(j, (i) + (j) + 4)                        \
    _Pragma("unroll")                                                    \
    for (int k = 0; k < 8; ++k) accA[k] += na * (float)a[k];             \
  }
#define SLB(j, i)                                                        \
  if ((i) + (j) < nB) {                                                  \
    bf16x8 a = vb##j; float na = sb##j;                                  \
    if ((i) + (j) + 4 < nB) LDB(j, (i) + (j) + 4)                        \
    _Pragma("unroll")                                                    \
    for (int k = 0; k < 8; ++k) accB[k] += na * (float)a[k];             \
  }

  if (0 < nA) LDA(0, 0)
  if (0 < nB) LDB(0, 0)
  if (1 < nA) LDA(1, 1)
  if (1 < nB) LDB(1, 1)
  if (2 < nA) LDA(2, 2)
  if (2 < nB) LDB(2, 2)
  if (3 < nA) LDA(3, 3)
  if (3 < nB) LDB(3, 3)

  for (int i = 0; i < nmax; i += 4) {
    SLA(0, i)
    SLB(0, i)
    SLA(1, i)
    SLB(1, i)
    SLA(2, i)
    SLB(2, i)
    SLA(3, i)
    SLB(3, i)
  }
#undef SLA
#undef SLB
#undef LDA
#undef LDB

  float ndA = 0.9f * nrm[nodeA];
  float ndB = 0.9f * nrm[nodeB];
  bf16x8 oA, oB;
#pragma unroll
  for (int k = 0; k < 8; ++k) {
    oA[k] = (bf16_t)(ndA * accA[k]);
    oB[k] = (bf16_t)(ndB * accB[k]);
  }
  *(bf16x8*)(Acat + (size_t)nodeA * 1024 + lane * 8) = oA;
  *(bf16x8*)(Acat + (size_t)nodeB * 1024 + lane * 8) = oB;
}

// -------- GEMM: C = A(MxK,bf16) @ B(Kx512), B given transposed BT[n][k] ------
// Round-2 verified structure (best measured: 53.1-53.7 us): tile 64x128,
// 4 waves (2x2, 32x64 each), BK=64, 2-buf LDS via global_load_lds,
// 1 barrier/iter, 48KB LDS -> 3 blocks/CU.
// Swizzle for 128B rows: stored chunk cc = global chunk gc ^ (row&7).
// XCD swizzle: bIdx = (m%8) + 8*(n + 4*(m/8)).
// MODE 0: h = acc + bias -> acat2[row*1024+512+col] = bf16(h)  (RAW h; 0.1 is
//         folded into BT weights / epilogue). blocks >= 1280 compute nrm[]
//         from cnt[] and exit (norm piggyback).
// MODE 1/2: fs = Acat[row][col] + 0.1*Acat[row][512+col];
//           r = relu((1-beta)*fs + beta*acc + bias) -> MODE1 bf16 outb, MODE2 f32 outf
template <int MODE>
__global__ __launch_bounds__(256) void gemm_kernel(
    const bf16_t* __restrict__ A, const bf16_t* __restrict__ BT,
    int lda, int ldb, int K, int M,
    const float* __restrict__ bias,
    const bf16_t* __restrict__ acat_ro, float beta,
    float* __restrict__ outf, bf16_t* __restrict__ outb,
    bf16_t* __restrict__ acat2,
    const int* __restrict__ cnt, float* __restrict__ nrm) {
  __shared__ bf16_t As[2][64 * 64];    // 8 KB per buf
  __shared__ bf16_t Bs[2][128 * 64];   // 16 KB per buf

  const int bid = blockIdx.x;
  if constexpr (MODE == 0) {
    if (bid >= 1280) {   // norm piggyback blocks
      int i = (bid - 1280) * 256 + threadIdx.x;
      if (i < NN) nrm[i] = 1.0f / sqrtf(fmaxf((float)cnt[i], 1.0f));
      return;
    }
  }
  const int mt = (bid >> 5) * 8 + (bid & 7);   // m-tile
  const int nt = (bid >> 3) & 3;               // n-tile
  const int m0 = mt * 64;
  if (m0 >= M) return;
  const int n0 = nt * 128;

  const int t = threadIdx.x;
  const int lane = t & 63;
  const int w = t >> 6;
  const int wm = w & 1, wn = w >> 1;
  const int quad = lane >> 4, m16 = lane & 15;

  // staging: LDS-linear chunk c_l -> row r=c_l>>3, slot cc=c_l&7 holds global
  // chunk gc = cc ^ (r&7). Thread t stages c_l = t (+256 [+512 +768 for B]).
  const int tr = t >> 3;
  const int gc = (t & 7) ^ (tr & 7);
  int arow0 = m0 + tr;      arow0 = arow0 < M ? arow0 : M - 1;  // clamp OOB
  int arow1 = m0 + tr + 32; arow1 = arow1 < M ? arow1 : M - 1;
  const bf16_t* agp0 = A + (size_t)arow0 * lda + gc * 8;
  const bf16_t* agp1 = A + (size_t)arow1 * lda + gc * 8;
  const bf16_t* bgp0 = BT + (size_t)(n0 + tr) * ldb + gc * 8;
  const bf16_t* bgp1 = BT + (size_t)(n0 + tr + 32) * ldb + gc * 8;
  const bf16_t* bgp2 = BT + (size_t)(n0 + tr + 64) * ldb + gc * 8;
  const bf16_t* bgp3 = BT + (size_t)(n0 + tr + 96) * ldb + gc * 8;

#define STAGE(buf, ko)                              \
  gload16(agp0 + (ko), &As[buf][t * 8]);            \
  gload16(agp1 + (ko), &As[buf][(t + 256) * 8]);    \
  gload16(bgp0 + (ko), &Bs[buf][t * 8]);            \
  gload16(bgp1 + (ko), &Bs[buf][(t + 256) * 8]);    \
  gload16(bgp2 + (ko), &Bs[buf][(t + 512) * 8]);    \
  gload16(bgp3 + (ko), &Bs[buf][(t + 768) * 8]);

  floatx4 acc[2][4] = {};
  const int niter = K >> 6;

  // stage buffer 0
  STAGE(0, 0)

  for (int kt = 0; kt < niter; ++kt) {
    __syncthreads();   // drains buf kt's loads (issued one iter ago)
    const int b = kt & 1;
    if (kt + 1 < niter) {        // prefetch next buffer during compute
      const int ko = (kt + 1) * 64;
      STAGE(b ^ 1, ko)
    }

#pragma unroll
    for (int ks = 0; ks < 2; ++ks) {
      bf16x8 af[2], bfr[4];
#pragma unroll
      for (int i = 0; i < 2; ++i) {
        int arow = wm * 32 + i * 16 + m16;
        int cc = (ks * 4 + quad) ^ (arow & 7);
        af[i] = *(const bf16x8*)(&As[b][(arow * 8 + cc) * 8]);
      }
#pragma unroll
      for (int j = 0; j < 4; ++j) {
        int brow = wn * 64 + j * 16 + m16;
        int cc = (ks * 4 + quad) ^ (brow & 7);
        bfr[j] = *(const bf16x8*)(&Bs[b][(brow * 8 + cc) * 8]);
      }
#pragma unroll
      for (int i = 0; i < 2; ++i)
#pragma unroll
        for (int j = 0; j < 4; ++j)
          acc[i][j] = __builtin_amdgcn_mfma_f32_16x16x32_bf16(af[i], bfr[j], acc[i][j], 0, 0, 0);
    }
  }
#undef STAGE

  // epilogue: C/D layout col = lane&15, row = quad*4 + reg
#pragma unroll
  for (int i = 0; i < 2; ++i) {
#pragma unroll
    for (int j = 0; j < 4; ++j) {
      int col = n0 + wn * 64 + j * 16 + m16;
      float bv = bias[col];
#pragma unroll
      for (int p = 0; p < 4; ++p) {
        int row = m0 + wm * 32 + i * 16 + quad * 4 + p;
        if (row < M) {
          float v = acc[i][j][p];
          if constexpr (MODE == 0) {
            // store RAW h into Acat h-half (0.1 folded into BT / epilogue)
            acat2[(size_t)row * 1024 + 512 + col] = (bf16_t)(v + bv);
          } else {
            size_t idx = (size_t)row * DD + col;
            float fsv = (float)acat_ro[(size_t)row * 1024 + col] +
                        0.1f * (float)acat_ro[(size_t)row * 1024 + 512 + col];
            float r = (1.0f - beta) * fsv + beta * v + bv;
            r = fmaxf(r, 0.0f);
            if constexpr (MODE == 1) outb[idx] = (bf16_t)r;
            else outf[idx] = r;
          }
        }
      }
    }
  }
}

extern "C" void kernel_launch(void* const* d_in, const int* in_sizes, int n_in,
                              void* d_out, int out_size, void* d_ws, size_t ws_size,
                              hipStream_t stream) {
  const float* feat = (const float*)d_in[0];
  const int* src = (const int*)d_in[1];
  const int* dst = (const int*)d_in[2];
  const float* fc_w = (const float*)d_in[3];
  const float* fc_b = (const float*)d_in[4];
  const float* w1_1 = (const float*)d_in[5];
  const float* w2_1 = (const float*)d_in[6];
  const float* b_1  = (const float*)d_in[7];
  const float* w1_2 = (const float*)d_in[8];
  const float* w2_2 = (const float*)d_in[9];
  const float* b_2  = (const float*)d_in[10];
  float* out = (float*)d_out;

  char* ws = (char*)d_ws;
  size_t off = 0;
  auto alloc = [&](size_t bytes) {
    char* p = ws + off;
    off += (bytes + 255) & ~(size_t)255;
    return p;
  };
  const size_t NDf = (size_t)NN * DD;               // 10.24M elements
  bf16_t* res_bf = (bf16_t*)alloc(NDf * sizeof(bf16_t));        // 20.48 MB
  bf16_t* featb  = (bf16_t*)alloc(NDf * sizeof(bf16_t));        // 20.48 MB
  bf16_t* Acat   = (bf16_t*)alloc((size_t)NN * 1024 * sizeof(bf16_t));  // 40.96 MB
  bf16_t* BW0    = (bf16_t*)alloc((size_t)512 * 512 * sizeof(bf16_t));
  bf16_t* BT1    = (bf16_t*)alloc((size_t)512 * 1024 * sizeof(bf16_t));
  bf16_t* BT2    = (bf16_t*)alloc((size_t)512 * 1024 * sizeof(bf16_t));
  int*    cnt    = (int*)alloc((size_t)NN * sizeof(int));
  float*  nrm    = (float*)alloc((size_t)NN * sizeof(float));
  int*    esrc   = (int*)alloc((size_t)NN * CAP * sizeof(int)); // 7.68 MB

  // 1. fused prep: featb/BW0/BT1/BT2 reformats (0.1 folded into W2) + cnt zero
  prep_kernel<<<PREP_BLOCKS, 256, 0, stream>>>(feat, fc_w, w1_1, w2_1, w1_2, w2_2,
                                               featb, BW0, BT1, BT2, cnt);
  // 2. bucket build (counts + slots in one pass)
  bucket_kernel<<<(EE + 255) / 256, 256, 0, stream>>>(src, dst, cnt, esrc, EE);

  // 313 m-tiles of 64 rows, 4 n-tiles; swizzled grid covers m<320 -> 1280 blocks
  // 3. h = feat @ fc_w^T + fc_b -> Acat h-half (raw); +79 norm piggyback blocks
  gemm_kernel<0><<<1280 + 79, 256, 0, stream>>>(featb, BW0, 512, 512, 512, NN, fc_b,
                                                nullptr, 0.0f, nullptr, nullptr, Acat,
                                                cnt, nrm);

  // ---- layer 1 ----  (aggregate reads h rows from Acat h-half, stride 1024)
  aggregate_kernel<<<NN / 8, 256, 0, stream>>>(Acat + 512, 1024, nrm, cnt, esrc, Acat);
  gemm_kernel<1><<<1280, 256, 0, stream>>>(Acat, BT1, 1024, 1024, 1024, NN, b_1,
                                           Acat, BETA1, nullptr, res_bf, nullptr,
                                           nullptr, nullptr);

  // ---- layer 2 ----  (aggregate reads res rows, stride 512)
  aggregate_kernel<<<NN / 8, 256, 0, stream>>>(res_bf, 512, nrm, cnt, esrc, Acat);
  gemm_kernel<2><<<1280, 256, 0, stream>>>(Acat, BT2, 1024, 1024, 1024, NN, b_2,
                                           Acat, BETA2, out, nullptr, nullptr,
                                           nullptr, nullptr);
}

// Round 10
// 342.616 us; speedup vs baseline: 1.1131x; 1.0814x over previous
//
#include <hip/hip_runtime.h>
#include <hip/hip_bf16.h>
#include <stdint.h>
#include <stddef.h>

typedef __bf16 bf16_t;
typedef __bf16 bf16x4 __attribute__((ext_vector_type(4)));
typedef __bf16 bf16x8 __attribute__((ext_vector_type(8)));
typedef float floatx4 __attribute__((ext_vector_type(4)));

#define NN 20000
#define EE 320000
#define DD 512
#define CAP 96
#define BETA1 0.6931471805599453f
#define BETA2 0.40546510810816444f

// async global->LDS, 16B per lane. LDS dest must be wave-uniform base + lane*16.
__device__ __forceinline__ void gload16(const bf16_t* g, bf16_t* l) {
  __builtin_amdgcn_global_load_lds((const __attribute__((address_space(1))) uint32_t*)g,
                                   (__attribute__((address_space(3))) uint32_t*)l, 16, 0, 0);
}

// ------- bucket fill with degree count: esrc[dst*CAP + cnt[dst]++] = src -----
__global__ __launch_bounds__(256) void bucket_kernel(
    const int* __restrict__ src, const int* __restrict__ dst,
    int* __restrict__ cnt, int* __restrict__ esrc, int E) {
  int e = blockIdx.x * 256 + threadIdx.x;
  if (e < E) {
    int d = dst[e];
    int pos = atomicAdd(&cnt[d], 1);
    if (pos < CAP) esrc[d * CAP + pos] = src[e];
  }
}

// ---------------- fused prep: zeroing + all weight/input reformats -----------
// sections by blockIdx:
//   [0, 5000)        featb: feat f32 row-major -> bf16 row-major (8 elem/thr)
//   [5000, 5128)     BW0:   fc_w f32 [n][k] -> bf16 row-major (= B^T layout)
//   [5128, 5384)     BT1:   [w1_1; 0.1*w2_1]^T -> bf16 BT[n][k], k<1024
//   [5384, 5640)     BT2:   [w1_2; 0.1*w2_2]^T -> bf16
//   [5640, 5719)     cnt zero
//   [5719, 7594)     esrc zero (int4) — padding slots read 0 (valid node) so
//                    the aggregate ring can ALWAYS issue its gathers (fixed
//                    vmcnt counts); FMA guards drop their contribution.
// 0.1 folded into the W2 half so Acat holds RAW h:
//   [f,h] @ [W1; 0.1W2]^T = f@W1 + 0.1*(h@W2)
#define PREP_BLOCKS 7594
__global__ __launch_bounds__(256) void prep_kernel(
    const float* __restrict__ feat, const float* __restrict__ fc_w,
    const float* __restrict__ w1_1, const float* __restrict__ w2_1,
    const float* __restrict__ w1_2, const float* __restrict__ w2_2,
    bf16_t* __restrict__ featb, bf16_t* __restrict__ bw0,
    bf16_t* __restrict__ bt1, bf16_t* __restrict__ bt2,
    int* __restrict__ cnt, int* __restrict__ esrc) {
  int b = blockIdx.x, t = threadIdx.x;
  if (b < 5128) {
    // straight cvt, 8 f32 -> bf16x8 per thread
    const float* in = (b < 5000) ? feat : fc_w;
    bf16_t* out = (b < 5000) ? featb : bw0;
    size_t c = (size_t)(b < 5000 ? b : b - 5000) * 256 + t;
    const float* s = in + c * 8;
    float4 v0 = *(const float4*)s, v1 = *(const float4*)(s + 4);
    bf16x8 o = {(bf16_t)v0.x, (bf16_t)v0.y, (bf16_t)v0.z, (bf16_t)v0.w,
                (bf16_t)v1.x, (bf16_t)v1.y, (bf16_t)v1.z, (bf16_t)v1.w};
    *(bf16x8*)(out + c * 8) = o;
  } else if (b < 5640) {
    // BT[n][k] = scale * W[k][n], W = [W1; W2] stacked in k. 8 k per thread.
    int base = (b < 5384) ? 5128 : 5384;
    const float* Wa = (b < 5384) ? w1_1 : w1_2;
    const float* Wb = (b < 5384) ? w2_1 : w2_2;
    bf16_t* bt = (b < 5384) ? bt1 : bt2;
    int c = (b - base) * 256 + t;        // [0, 65536)
    int n = c >> 7, kc = c & 127;
    const float* W = (kc < 64) ? Wa : Wb;
    const float sc = (kc < 64) ? 1.0f : 0.1f;   // fold ALPHA into W2 half
    int kcw = kc & 63;
    bf16x8 o;
#pragma unroll
    for (int e = 0; e < 8; ++e)
      o[e] = (bf16_t)(sc * W[(size_t)(kcw * 8 + e) * 512 + n]);   // column-n gather
    *(bf16x8*)(bt + (size_t)n * 1024 + kc * 8) = o;
  } else if (b < 5719) {
    int i = (b - 5640) * 256 + t;
    if (i < NN) cnt[i] = 0;
  } else {
    int i = (b - 5719) * 256 + t;        // 480000 int4 = NN*CAP ints exactly
    ((int4*)esrc)[i] = make_int4(0, 0, 0, 0);
  }
}

// ---------- bucket aggregate: one wave per dst node, LDS-DMA gather ring -----
// f = 0.9 * rsqrt(deg[node]) * sum_e hs[src_e]        (hs pre-scaled by nrm)
// Acat[node][0:512] = bf16(f)   (h-half of Acat untouched, layer-invariant)
// Round 10: rounds 5/6/9 proved hipcc register-minimizes gather pipelines
// (round-9 VGPR=44 -> MLP~1-2, 63us latency-bound). global_load_lds needs NO
// dest VGPRs: per-wave private 2x4-slot LDS ring (8KB/wave, no barriers),
// counted vmcnt keeps 4x1KB gathers + 1 idx load permanently in flight.
// Fixed issue order per chunk c (fenced by "memory"-clobber waits, so the
// compiler cannot migrate memory ops between sections):
//   [entering: idx(c+1) 1 op (oldest), ring(c) 4 ops]
//   vmcnt(4) -> idx(c+1) ready | issue idx(c+2) | issue ring(c+1) (4)
//   vmcnt(5) -> ring(c) landed | ds_read_b128 x4 + guarded adds
// Issues are NEVER guarded out (offsets clamped, esrc zero-padded) so the
// counts are exact; per-edge guards keep the math correct.
__global__ __launch_bounds__(256) void aggregate_kernel(
    const bf16_t* __restrict__ hs, const int* __restrict__ cnt,
    const int* __restrict__ esrc, bf16_t* __restrict__ Acat) {
  __shared__ bf16_t ring[4][2][4][512];   // 4 waves x 2 bufs x 4 slots x 1KB = 32KB
  const int w = threadIdx.x >> 6;
  const int lane = threadIdx.x & 63;
  const int node = blockIdx.x * 4 + w;    // grid 5000 x 4 waves = 20000 exact
  const int* eb = esrc + (size_t)node * CAP;
  int ncnt = cnt[node];
  int n_e = ncnt < CAP ? ncnt : CAP;
  float nd = 0.9f * rsqrtf(fmaxf((float)ncnt, 1.0f));
  int nchunks = (n_e + 3) >> 2;

  float acc[8] = {};
  bf16_t* r0base = &ring[w][0][0][lane * 8];
  bf16_t* r1base = &ring[w][1][0][lane * 8];

  int4 icur, inext;

  // clean slate: cnt load retired before pipeline counting starts
  asm volatile("s_waitcnt vmcnt(0)" ::: "memory");
  __builtin_amdgcn_sched_barrier(0);
  icur = *(const int4*)(eb);                   // idx(0)
  asm volatile("s_waitcnt vmcnt(0)" ::: "memory");
  __builtin_amdgcn_sched_barrier(0);
  inext = *(const int4*)(eb + 4);              // idx(1)  [issued BEFORE ring(0)]
  gload16(hs + (size_t)icur.x * DD + lane * 8, r0base);
  gload16(hs + (size_t)icur.y * DD + lane * 8, r0base + 512);
  gload16(hs + (size_t)icur.z * DD + lane * 8, r0base + 1024);
  gload16(hs + (size_t)icur.w * DD + lane * 8, r0base + 1536);

  for (int c = 0; c < nchunks; ++c) {
    // retire idx(c+1) (oldest); ring(c) stays in flight
    asm volatile("s_waitcnt vmcnt(4)" ::: "memory");
    __builtin_amdgcn_sched_barrier(0);
    int4 iuse = inext;
    int off2 = (c + 2) * 4; off2 = off2 > CAP - 4 ? CAP - 4 : off2;
    inext = *(const int4*)(eb + off2);         // idx(c+2): 1 op
    bf16_t* rbn = ((c + 1) & 1) ? r1base : r0base;
    gload16(hs + (size_t)iuse.x * DD + lane * 8, rbn);
    gload16(hs + (size_t)iuse.y * DD + lane * 8, rbn + 512);
    gload16(hs + (size_t)iuse.z * DD + lane * 8, rbn + 1024);
    gload16(hs + (size_t)iuse.w * DD + lane * 8, rbn + 1536);
    // retire ring(c) (oldest 4); keep idx(c+2) + ring(c+1) = 5 in flight
    asm volatile("s_waitcnt vmcnt(5)" ::: "memory");
    __builtin_amdgcn_sched_barrier(0);
    bf16_t* rb = (c & 1) ? r1base : r0base;
    bf16x8 v0 = *(const bf16x8*)(rb);
    bf16x8 v1 = *(const bf16x8*)(rb + 512);
    bf16x8 v2 = *(const bf16x8*)(rb + 1024);
    bf16x8 v3 = *(const bf16x8*)(rb + 1536);
    int e0 = c * 4;
    if (e0 < n_e) {
#pragma unroll
      for (int k = 0; k < 8; ++k) acc[k] += (float)v0[k];
    }
    if (e0 + 1 < n_e) {
#pragma unroll
      for (int k = 0; k < 8; ++k) acc[k] += (float)v1[k];
    }
    if (e0 + 2 < n_e) {
#pragma unroll
      for (int k = 0; k < 8; ++k) acc[k] += (float)v2[k];
    }
    if (e0 + 3 < n_e) {
#pragma unroll
      for (int k = 0; k < 8; ++k) acc[k] += (float)v3[k];
    }
  }

  bf16x8 ob;
#pragma unroll
  for (int k = 0; k < 8; ++k) ob[k] = (bf16_t)(nd * acc[k]);
  *(bf16x8*)(Acat + (size_t)node * 1024 + lane * 8) = ob;
}

// -------- GEMM: C = A(MxK,bf16) @ B(Kx512), B given transposed BT[n][k] ------
// Round-2 verified structure (best measured): tile 64x128, 4 waves (2x2,
// 32x64 each), BK=64, 2-buf LDS via global_load_lds, 1 barrier/iter, 48KB LDS.
// Swizzle for 128B rows: stored chunk cc = global chunk gc ^ (row&7).
// XCD swizzle: bIdx = (m%8) + 8*(n + 4*(m/8)).
// nrm[] array is gone: rsqrt(cnt[row]) computed inline in epilogues.
// MODE 0: h = acc+bias -> acat2[row*1024+512+col]=bf16(h) (raw, for f0) AND
//         outb[row*512+col] = bf16(nrm_row*h)  (hs: pre-scaled aggregate input)
// MODE 1: fs = Acat[row][col] + 0.1*Acat[row][512+col];
//         r = relu((1-beta)*fs + beta*acc + bias);
//         outb[idx] = bf16(nrm_row*r)          (res_bf: pre-scaled agg-2 input)
// MODE 2: same r -> outf[idx] = r (f32 final output)
template <int MODE>
__global__ __launch_bounds__(256) void gemm_kernel(
    const bf16_t* __restrict__ A, const bf16_t* __restrict__ BT,
    int lda, int ldb, int K, int M,
    const float* __restrict__ bias,
    const bf16_t* __restrict__ acat_ro, float beta,
    float* __restrict__ outf, bf16_t* __restrict__ outb,
    bf16_t* __restrict__ acat2,
    const int* __restrict__ cnt) {
  __shared__ bf16_t As[2][64 * 64];    // 8 KB per buf
  __shared__ bf16_t Bs[2][128 * 64];   // 16 KB per buf

  const int bid = blockIdx.x;
  const int mt = (bid >> 5) * 8 + (bid & 7);   // m-tile
  const int nt = (bid >> 3) & 3;               // n-tile
  const int m0 = mt * 64;
  if (m0 >= M) return;
  const int n0 = nt * 128;

  const int t = threadIdx.x;
  const int lane = t & 63;
  const int w = t >> 6;
  const int wm = w & 1, wn = w >> 1;
  const int quad = lane >> 4, m16 = lane & 15;

  // staging: LDS-linear chunk c_l -> row r=c_l>>3, slot cc=c_l&7 holds global
  // chunk gc = cc ^ (r&7). Thread t stages c_l = t (+256 [+512 +768 for B]).
  const int tr = t >> 3;
  const int gc = (t & 7) ^ (tr & 7);
  int arow0 = m0 + tr;      arow0 = arow0 < M ? arow0 : M - 1;  // clamp OOB
  int arow1 = m0 + tr + 32; arow1 = arow1 < M ? arow1 : M - 1;
  const bf16_t* agp0 = A + (size_t)arow0 * lda + gc * 8;
  const bf16_t* agp1 = A + (size_t)arow1 * lda + gc * 8;
  const bf16_t* bgp0 = BT + (size_t)(n0 + tr) * ldb + gc * 8;
  const bf16_t* bgp1 = BT + (size_t)(n0 + tr + 32) * ldb + gc * 8;
  const bf16_t* bgp2 = BT + (size_t)(n0 + tr + 64) * ldb + gc * 8;
  const bf16_t* bgp3 = BT + (size_t)(n0 + tr + 96) * ldb + gc * 8;

#define STAGE(buf, ko)                              \
  gload16(agp0 + (ko), &As[buf][t * 8]);            \
  gload16(agp1 + (ko), &As[buf][(t + 256) * 8]);    \
  gload16(bgp0 + (ko), &Bs[buf][t * 8]);            \
  gload16(bgp1 + (ko), &Bs[buf][(t + 256) * 8]);    \
  gload16(bgp2 + (ko), &Bs[buf][(t + 512) * 8]);    \
  gload16(bgp3 + (ko), &Bs[buf][(t + 768) * 8]);

  floatx4 acc[2][4] = {};
  const int niter = K >> 6;

  // stage buffer 0
  STAGE(0, 0)

  for (int kt = 0; kt < niter; ++kt) {
    __syncthreads();   // drains buf kt's loads (issued one iter ago)
    const int b = kt & 1;
    if (kt + 1 < niter) {        // prefetch next buffer during compute
      const int ko = (kt + 1) * 64;
      STAGE(b ^ 1, ko)
    }

#pragma unroll
    for (int ks = 0; ks < 2; ++ks) {
      bf16x8 af[2], bfr[4];
#pragma unroll
      for (int i = 0; i < 2; ++i) {
        int arow = wm * 32 + i * 16 + m16;
        int cc = (ks * 4 + quad) ^ (arow & 7);
        af[i] = *(const bf16x8*)(&As[b][(arow * 8 + cc) * 8]);
      }
#pragma unroll
      for (int j = 0; j < 4; ++j) {
        int brow = wn * 64 + j * 16 + m16;
        int cc = (ks * 4 + quad) ^ (brow & 7);
        bfr[j] = *(const bf16x8*)(&Bs[b][(brow * 8 + cc) * 8]);
      }
#pragma unroll
      for (int i = 0; i < 2; ++i)
#pragma unroll
        for (int j = 0; j < 4; ++j)
          acc[i][j] = __builtin_amdgcn_mfma_f32_16x16x32_bf16(af[i], bfr[j], acc[i][j], 0, 0, 0);
    }
  }
#undef STAGE

  // per-thread row rsqrt(cnt) (MODE 0/1 pre-scale writes). 8 unique rows.
  float rsv[2][4];
  if constexpr (MODE != 2) {
#pragma unroll
    for (int i = 0; i < 2; ++i)
#pragma unroll
      for (int p = 0; p < 4; ++p) {
        int row = m0 + wm * 32 + i * 16 + quad * 4 + p;
        int rowc = row < M ? row : M - 1;
        rsv[i][p] = rsqrtf(fmaxf((float)cnt[rowc], 1.0f));
      }
  }

  // epilogue: C/D layout col = lane&15, row = quad*4 + reg
#pragma unroll
  for (int i = 0; i < 2; ++i) {
#pragma unroll
    for (int j = 0; j < 4; ++j) {
      int col = n0 + wn * 64 + j * 16 + m16;
      float bv = bias[col];
#pragma unroll
      for (int p = 0; p < 4; ++p) {
        int row = m0 + wm * 32 + i * 16 + quad * 4 + p;
        if (row < M) {
          float v = acc[i][j][p];
          if constexpr (MODE == 0) {
            float hv = v + bv;
            acat2[(size_t)row * 1024 + 512 + col] = (bf16_t)hv;        // raw h (f0)
            outb[(size_t)row * DD + col] = (bf16_t)(rsv[i][p] * hv);   // hs
          } else {
            size_t idx = (size_t)row * DD + col;
            float fsv = (float)acat_ro[(size_t)row * 1024 + col] +
                        0.1f * (float)acat_ro[(size_t)row * 1024 + 512 + col];
            float r = (1.0f - beta) * fsv + beta * v + bv;
            r = fmaxf(r, 0.0f);
            if constexpr (MODE == 1) outb[idx] = (bf16_t)(rsv[i][p] * r);  // res'
            else outf[idx] = r;
          }
        }
      }
    }
  }
}

extern "C" void kernel_launch(void* const* d_in, const int* in_sizes, int n_in,
                              void* d_out, int out_size, void* d_ws, size_t ws_size,
                              hipStream_t stream) {
  const float* feat = (const float*)d_in[0];
  const int* src = (const int*)d_in[1];
  const int* dst = (const int*)d_in[2];
  const float* fc_w = (const float*)d_in[3];
  const float* fc_b = (const float*)d_in[4];
  const float* w1_1 = (const float*)d_in[5];
  const float* w2_1 = (const float*)d_in[6];
  const float* b_1  = (const float*)d_in[7];
  const float* w1_2 = (const float*)d_in[8];
  const float* w2_2 = (const float*)d_in[9];
  const float* b_2  = (const float*)d_in[10];
  float* out = (float*)d_out;

  char* ws = (char*)d_ws;
  size_t off = 0;
  auto alloc = [&](size_t bytes) {
    char* p = ws + off;
    off += (bytes + 255) & ~(size_t)255;
    return p;
  };
  const size_t NDf = (size_t)NN * DD;               // 10.24M elements
  bf16_t* res_bf = (bf16_t*)alloc(NDf * sizeof(bf16_t));        // 20.48 MB (nrm*res)
  bf16_t* featb  = (bf16_t*)alloc(NDf * sizeof(bf16_t));        // 20.48 MB
  bf16_t* hs     = (bf16_t*)alloc(NDf * sizeof(bf16_t));        // 20.48 MB (nrm*h)
  bf16_t* Acat   = (bf16_t*)alloc((size_t)NN * 1024 * sizeof(bf16_t));  // 40.96 MB
  bf16_t* BW0    = (bf16_t*)alloc((size_t)512 * 512 * sizeof(bf16_t));
  bf16_t* BT1    = (bf16_t*)alloc((size_t)512 * 1024 * sizeof(bf16_t));
  bf16_t* BT2    = (bf16_t*)alloc((size_t)512 * 1024 * sizeof(bf16_t));
  int*    cnt    = (int*)alloc((size_t)NN * sizeof(int));
  int*    esrc   = (int*)alloc(((size_t)NN * CAP + 64) * sizeof(int)); // 7.68 MB + pad

  // 1. fused prep: featb/BW0/BT1/BT2 reformats + cnt zero + esrc zero
  prep_kernel<<<PREP_BLOCKS, 256, 0, stream>>>(feat, fc_w, w1_1, w2_1, w1_2, w2_2,
                                               featb, BW0, BT1, BT2, cnt, esrc);
  // 2. bucket build (counts + slots in one pass)
  bucket_kernel<<<(EE + 255) / 256, 256, 0, stream>>>(src, dst, cnt, esrc, EE);

  // 313 m-tiles of 64 rows, 4 n-tiles; swizzled grid covers m<320 -> 1280 blocks
  // 3. h = feat @ fc_w^T + fc_b -> Acat h-half (raw) + hs (nrm*h)
  gemm_kernel<0><<<1280, 256, 0, stream>>>(featb, BW0, 512, 512, 512, NN, fc_b,
                                           nullptr, 0.0f, nullptr, hs, Acat, cnt);

  // ---- layer 1 ----
  aggregate_kernel<<<NN / 4, 256, 0, stream>>>(hs, cnt, esrc, Acat);
  gemm_kernel<1><<<1280, 256, 0, stream>>>(Acat, BT1, 1024, 1024, 1024, NN, b_1,
                                           Acat, BETA1, nullptr, res_bf, nullptr, cnt);

  // ---- layer 2 ----
  aggregate_kernel<<<NN / 4, 256, 0, stream>>>(res_bf, cnt, esrc, Acat);
  gemm_kernel<2><<<1280, 256, 0, stream>>>(Acat, BT2, 1024, 1024, 1024, NN, b_2,
                                           Acat, BETA2, out, nullptr, nullptr, nullptr);
}